// Round 15
// baseline (212.477 us; speedup 1.0000x reference)
//
#include <hip/hip_runtime.h>
#include <hip/hip_bf16.h>

// LSTM cell, B=8192, IN=H=1024.
// R15: B (weights) direct global->register (L2-resident panel), A-only LDS.
// LDS traffic/tile 224->144 KB; 1 barrier + 1 vmcnt(8) per K-tile; B latency
// handled by compiler counted vmcnt on plain loads; A gloads pinned before B
// loads via sched_barrier(0) so vmcnt(8) retires exactly the 4 A-gloads.

#define B_DIM 8192
#define H_DIM 1024
#define BH (8192 * 1024)
#define K2 2048

typedef __attribute__((ext_vector_type(4))) float f32x4;
typedef __attribute__((ext_vector_type(8))) __bf16 bf16x8;
typedef __attribute__((ext_vector_type(8))) unsigned short ushort8;

static __device__ __forceinline__ unsigned short f2bf(float f) {
    return __builtin_bit_cast(unsigned short, (__bf16)f);
}
static __device__ __forceinline__ float sigf(float x) {
    return 1.0f / (1.0f + __expf(-x));
}
static __device__ __forceinline__ float tanhft(float x) {
    float e = __expf(2.0f * x);
    return (e - 1.0f) / (e + 1.0f);
}
static __device__ __forceinline__ void gload16(const void* g, void* l) {
    __builtin_amdgcn_global_load_lds(
        (const __attribute__((address_space(1))) unsigned int*)g,
        (__attribute__((address_space(3))) unsigned int*)l, 16, 0, 0);
}
static __device__ __forceinline__ ushort8 cvt8(const float* src) {
    const float4 u = ((const float4*)src)[0];
    const float4 v = ((const float4*)src)[1];
    ushort8 o;
    o[0] = f2bf(u.x); o[1] = f2bf(u.y); o[2] = f2bf(u.z); o[3] = f2bf(u.w);
    o[4] = f2bf(v.x); o[5] = f2bf(v.y); o[6] = f2bf(v.z); o[7] = f2bf(v.w);
    return o;
}

// ---- merged conversion kernel (identical to R13/R14) ----
__global__ __launch_bounds__(256) void conv_kernel(
    const float* __restrict__ x, const float* __restrict__ h,
    const float* __restrict__ Wx, const float* __restrict__ Wh,
    unsigned short* __restrict__ A, unsigned short* __restrict__ W)
{
    const int bidx = blockIdx.x;
    if (bidx < 8192) {
        const int id = bidx * 256 + threadIdx.x;
        const int base = id * 8;
        const int b = base >> 11;
        const int k = base & 2047;
        const float* src = (k < 1024) ? (x + (size_t)b * 1024 + k)
                                      : (h + (size_t)b * 1024 + (k - 1024));
        *(ushort8*)(A + base) = cvt8(src);
    } else {
        const int id = (bidx - 8192) * 256 + threadIdx.x;
        const int base = id * 8;
        const int n = base >> 11;
        const int k = base & 2047;
        const int jb = n >> 8, wn = (n >> 6) & 3, g = (n >> 4) & 3, jj = n & 15;
        const int srow = (g << 10) + (jb << 6) + (wn << 4) + jj;
        const float* src = (k < 1024) ? (Wx + (size_t)srow * 1024 + k)
                                      : (Wh + (size_t)srow * 1024 + (k - 1024));
        *(ushort8*)(W + base) = cvt8(src);
    }
}

// ==================== 256x256 GEMM, A-in-LDS + B-in-registers ====================
// LDS 64 KiB (u16 units): buf*16384; element (row r[0,256), k[0,64)):
// r*64 + ((k8 ^ (r&7))<<3) + (k&7). Stage quarter QA: linear dest, pre-swz src.
__global__ __launch_bounds__(512, 2) void lstm_gemm_br(
    const unsigned short* __restrict__ Abf, const unsigned short* __restrict__ Wbf,
    const float* __restrict__ bx, const float* __restrict__ bh,
    const float* __restrict__ cprev, float* __restrict__ out)
{
    extern __shared__ unsigned short lds[];

    const int tid = threadIdx.x;
    const int lane = tid & 63;
    const int wv = tid >> 6;
    const int wm = wv >> 2;          // 0..1
    const int wn = wv & 3;           // 0..3
    const int q = lane >> 4, c = lane & 15;

    // XCD-local jb-pair ordering
    const int bid = blockIdx.x;      // 0..511
    const int xcd = bid & 7;
    const int idx = bid >> 3;        // 0..63
    const int jb  = xcd * 2 + (idx & 1);   // 0..15
    const int bb  = idx >> 1;              // 0..31
    const int b0 = bb * 256;

    const unsigned short* Ab = Abf + (size_t)b0 * K2;
    const unsigned short* Wb = Wbf + (size_t)(jb * 256) * K2;

    // A staging: thread covers row = QA*64 + (tid>>3), global chunk pre-swizzled
    const size_t ssg = (size_t)(tid >> 3) * K2
                     + (size_t)(((tid & 7) ^ ((tid >> 3) & 7)) * 8);
    const unsigned sbase = (unsigned)(tid & 448) * 8;  // wave-uniform dest base

    // A fragment reads (swizzled LDS)
    const unsigned arow = (unsigned)(wm * 128 + c) * 64;
    const unsigned cach = (unsigned)((q ^ (c & 7)) << 3);

    // B direct-from-global per-lane base: row = jb*256 + wn*64 + g*16 + c
    const unsigned short* Wbp = Wb + (size_t)(wn * 64 + c) * K2 + (size_t)q * 8;

    f32x4 acc[8][4];
#pragma unroll
    for (int m = 0; m < 8; ++m)
#pragma unroll
        for (int g = 0; g < 4; ++g) acc[m][g] = f32x4{0.f, 0.f, 0.f, 0.f};

    bf16x8 av[4];
    bf16x8 bvA[2][4], bvB[2][4];   // [ks][gate], two banks (lead-1)

#define STG(BUF, QA, T) do {                                                   \
    gload16(Ab + ssg + (size_t)(QA) * 64 * K2 + (size_t)((T) & 31) * 64,       \
            &lds[(BUF) * 16384 + (QA) * 4096 + sbase]);                        \
} while (0)

#define LDB(DST, T) do {                                                       \
    const unsigned short* _w = Wbp + (size_t)((T) & 31) * 64;                  \
    DST[0][0] = *(const bf16x8*)(_w);                                          \
    DST[1][0] = *(const bf16x8*)(_w + 32);                                     \
    DST[0][1] = *(const bf16x8*)(_w + (size_t)16 * K2);                        \
    DST[1][1] = *(const bf16x8*)(_w + (size_t)16 * K2 + 32);                   \
    DST[0][2] = *(const bf16x8*)(_w + (size_t)32 * K2);                        \
    DST[1][2] = *(const bf16x8*)(_w + (size_t)32 * K2 + 32);                   \
    DST[0][3] = *(const bf16x8*)(_w + (size_t)48 * K2);                        \
    DST[1][3] = *(const bf16x8*)(_w + (size_t)48 * K2 + 32);                   \
} while (0)

#define LOADA(BUF, KS, MH) do {                                                \
    const unsigned short* _p = lds + (BUF) * 16384 + (MH) * 4096 + arow        \
                             + (cach ^ ((KS) * 32));                           \
    av[0] = *(const bf16x8*)(_p);                                              \
    av[1] = *(const bf16x8*)(_p + 1024);                                       \
    av[2] = *(const bf16x8*)(_p + 2048);                                       \
    av[3] = *(const bf16x8*)(_p + 3072);                                       \
} while (0)

#define MFMA16(MH, BV, KS) do {                                                \
    __builtin_amdgcn_s_setprio(1);                                             \
    _Pragma("unroll")                                                          \
    for (int _i = 0; _i < 4; ++_i)                                             \
        _Pragma("unroll")                                                      \
        for (int _g = 0; _g < 4; ++_g)                                         \
            acc[(MH) * 4 + _i][_g] = __builtin_amdgcn_mfma_f32_16x16x32_bf16(  \
                av[_i], BV[KS][_g], acc[(MH) * 4 + _i][_g], 0, 0, 0);          \
    __builtin_amdgcn_s_setprio(0);                                             \
} while (0)

#define BAR()  __builtin_amdgcn_s_barrier()
#define SCHB() __builtin_amdgcn_sched_barrier(0)
#define WVM8() asm volatile("s_waitcnt vmcnt(8)" ::: "memory")

// Per K-tile: stage A(t+1) (4 gloads, pinned first), load B(t+1) regs (8 plain
// loads), 16 ds_read + 64 MFMA (compiler counted waits), vmcnt(8) retires the
// 4 A-gloads, one barrier.
#define TILE(BUF, BVC, BVN, T1) do {                                           \
    STG((BUF) ^ 1, 0, T1); STG((BUF) ^ 1, 1, T1);                              \
    STG((BUF) ^ 1, 2, T1); STG((BUF) ^ 1, 3, T1);                              \
    SCHB();                                                                    \
    LDB(BVN, T1);                                                              \
    LOADA(BUF, 0, 0); MFMA16(0, BVC, 0);                                       \
    LOADA(BUF, 0, 1); MFMA16(1, BVC, 0);                                       \
    LOADA(BUF, 1, 0); MFMA16(0, BVC, 1);                                       \
    LOADA(BUF, 1, 1); MFMA16(1, BVC, 1);                                       \
    WVM8(); BAR();                                                             \
} while (0)

    // prologue: A(t0)->buf0 (4 gloads), B(t0)->bvA (8 loads); retire A0 only
    STG(0, 0, 0); STG(0, 1, 0); STG(0, 2, 0); STG(0, 3, 0);
    SCHB();
    LDB(bvA, 0);
    WVM8();
    BAR();

    for (int u = 0; u < 32; u += 2) {
        TILE(0, bvA, bvB, u + 1);   // tile u (buf0, B=bvA), prefetch u+1
        TILE(1, bvB, bvA, u + 2);   // tile u+1 (buf1, B=bvB), prefetch u+2
    }

#undef TILE
#undef STG
#undef LDB
#undef LOADA
#undef MFMA16

    // ---- fused LSTM epilogue (C/D: col=lane&15, row=(lane>>4)*4+rr) ----
    const int j = jb * 64 + wn * 16 + c;
    const float bI = bx[j] + bh[j];
    const float bF = bx[1024 + j] + bh[1024 + j];
    const float bG = bx[2048 + j] + bh[2048 + j];
    const float bO = bx[3072 + j] + bh[3072 + j];
#pragma unroll
    for (int mt = 0; mt < 8; ++mt) {
#pragma unroll
        for (int rr = 0; rr < 4; ++rr) {
            const int row = b0 + wm * 128 + mt * 16 + q * 4 + rr;
            const size_t off = (size_t)row * 1024 + j;
            const float iv = sigf(acc[mt][0][rr] + bI);
            const float fv = sigf(acc[mt][1][rr] + bF);
            const float gv = tanhft(acc[mt][2][rr] + bG);
            const float ov = sigf(acc[mt][3][rr] + bO);
            const float cp = cprev[off];
            const float nc = fv * cp + iv * gv;
            out[off] = ov * tanhft(nc);   // new_h
            out[BH + off] = nc;           // new_c
        }
    }
}

// ================== fallback (R2 128^2 kernel) if ws too small ==================
__global__ __launch_bounds__(256) void lstm_fallback(
    const float* __restrict__ incoming, const float* __restrict__ state,
    const float* __restrict__ Wx, const float* __restrict__ bx,
    const float* __restrict__ Wh, const float* __restrict__ bh,
    float* __restrict__ out)
{
    __shared__ unsigned short lA[128 * 64];
    __shared__ unsigned short lW[128 * 64];
    const int t = threadIdx.x;
    const int lane = t & 63;
    const int wv = t >> 6;
    const int q = lane >> 4;
    const int c = lane & 15;
    const int j0 = blockIdx.x * 32;
    const int b0 = blockIdx.y * 128;
    const float* hprev = state;
    const float* cprev = state + (size_t)BH;

    f32x4 acc[2][8];
#pragma unroll
    for (int mt = 0; mt < 2; ++mt)
#pragma unroll
        for (int nt = 0; nt < 8; ++nt)
            acc[mt][nt] = f32x4{0.f, 0.f, 0.f, 0.f};

    const int sr = t >> 3;
    const int sk8 = t & 7;

    for (int it = 0; it < 32; ++it) {
        const bool first = (it < 16);
        const float* As = first ? incoming : hprev;
        const float* Ws = first ? Wx : Wh;
        const int kk = first ? it * 64 : it * 64 - 1024;
#pragma unroll
        for (int i = 0; i < 4; ++i) {
            const int r = i * 32 + sr;
            *(ushort8*)&lA[r * 64 + ((sk8 ^ (r & 7)) * 8)] =
                cvt8(As + (size_t)(b0 + r) * 1024 + kk + sk8 * 8);
        }
#pragma unroll
        for (int i = 0; i < 4; ++i) {
            const int n = i * 32 + sr;
            const int grow = ((n >> 5) << 10) + j0 + (n & 31);
            *(ushort8*)&lW[n * 64 + ((sk8 ^ (n & 7)) * 8)] =
                cvt8(Ws + (size_t)grow * 1024 + kk + sk8 * 8);
        }
        __syncthreads();
#pragma unroll
        for (int ks = 0; ks < 2; ++ks) {
            const int k8a = ks * 4 + q;
            bf16x8 av[2], bv[8];
#pragma unroll
            for (int mt = 0; mt < 2; ++mt) {
                const int r = wv * 32 + mt * 16 + c;
                av[mt] = *(const bf16x8*)&lA[r * 64 + ((k8a ^ (r & 7)) * 8)];
            }
#pragma unroll
            for (int nt = 0; nt < 8; ++nt) {
                const int n = nt * 16 + c;
                bv[nt] = *(const bf16x8*)&lW[n * 64 + ((k8a ^ (n & 7)) * 8)];
            }
#pragma unroll
            for (int mt = 0; mt < 2; ++mt)
#pragma unroll
                for (int nt = 0; nt < 8; ++nt)
                    acc[mt][nt] = __builtin_amdgcn_mfma_f32_16x16x32_bf16(
                        av[mt], bv[nt], acc[mt][nt], 0, 0, 0);
        }
        __syncthreads();
    }

    const int b0r = b0 + wv * 32;
#pragma unroll
    for (int jt = 0; jt < 2; ++jt) {
        const int j = j0 + jt * 16 + c;
        const float bI = bx[j] + bh[j];
        const float bF = bx[1024 + j] + bh[1024 + j];
        const float bG = bx[2048 + j] + bh[2048 + j];
        const float bO = bx[3072 + j] + bh[3072 + j];
#pragma unroll
        for (int mt = 0; mt < 2; ++mt) {
#pragma unroll
            for (int rr = 0; rr < 4; ++rr) {
                const int row = b0r + mt * 16 + q * 4 + rr;
                const size_t off = (size_t)row * 1024 + j;
                const float iv = sigf(acc[mt][0 + jt][rr] + bI);
                const float fv = sigf(acc[mt][2 + jt][rr] + bF);
                const float gv = tanhft(acc[mt][4 + jt][rr] + bG);
                const float ov = sigf(acc[mt][6 + jt][rr] + bO);
                const float cp = cprev[off];
                const float nc = fv * cp + iv * gv;
                out[off] = ov * tanhft(nc);
                out[BH + off] = nc;
            }
        }
    }
}

extern "C" void kernel_launch(void* const* d_in, const int* in_sizes, int n_in,
                              void* d_out, int out_size, void* d_ws, size_t ws_size,
                              hipStream_t stream) {
    const float* incoming = (const float*)d_in[0];
    const float* state    = (const float*)d_in[1];
    const float* Wx       = (const float*)d_in[2];
    const float* bx       = (const float*)d_in[3];
    const float* Wh       = (const float*)d_in[4];
    const float* bh       = (const float*)d_in[5];
    float* out = (float*)d_out;

    const float* hprev = state;
    const float* cprev = state + (size_t)BH;

    const size_t A_bytes = (size_t)B_DIM * K2 * 2;       // 32 MiB
    const size_t W_bytes = (size_t)4 * H_DIM * K2 * 2;   // 16 MiB

    if (ws_size >= A_bytes + W_bytes) {
        unsigned short* Abf = (unsigned short*)d_ws;
        unsigned short* Wbf = (unsigned short*)((char*)d_ws + A_bytes);
        conv_kernel<<<dim3(12288), dim3(256), 0, stream>>>(
            incoming, hprev, Wx, Wh, Abf, Wbf);
        (void)hipFuncSetAttribute((const void*)lstm_gemm_br,
                                  hipFuncAttributeMaxDynamicSharedMemorySize, 65536);
        lstm_gemm_br<<<dim3(512), dim3(512), 65536, stream>>>(
            Abf, Wbf, bx, bh, cprev, out);
    } else {
        dim3 grid(H_DIM / 32, B_DIM / 128);
        lstm_fallback<<<grid, dim3(256), 0, stream>>>(
            incoming, state, Wx, bx, Wh, bh, out);
    }
}

// Round 16
// 159.363 us; speedup vs baseline: 1.3333x; 1.3333x over previous
//
#include <hip/hip_runtime.h>
#include <hip/hip_bf16.h>

// LSTM cell, B=8192, IN=H=1024.
// R16 (FINAL): revert to R14 — best verified (total ~159-160 us, gemm ~143 us).
// Structure: fp32->bf16 pre-convert (A=[x|h], W=[Wx|Wh] row-permuted) into d_ws;
// 256x256 bf16 GEMM, 128B-row XOR-swizzled LDS (conflict-free), global_load_lds
// line-coalesced staging, 4 single-barrier phases + counted vmcnt(2) per K-tile,
// setprio around MFMA, XCD-local jb-pairs, fused register-local LSTM epilogue.

#define B_DIM 8192
#define H_DIM 1024
#define BH (8192 * 1024)
#define K2 2048

typedef __attribute__((ext_vector_type(4))) float f32x4;
typedef __attribute__((ext_vector_type(8))) __bf16 bf16x8;
typedef __attribute__((ext_vector_type(8))) unsigned short ushort8;

static __device__ __forceinline__ unsigned short f2bf(float f) {
    return __builtin_bit_cast(unsigned short, (__bf16)f);
}
static __device__ __forceinline__ float sigf(float x) {
    return 1.0f / (1.0f + __expf(-x));
}
static __device__ __forceinline__ float tanhft(float x) {
    float e = __expf(2.0f * x);
    return (e - 1.0f) / (e + 1.0f);
}
static __device__ __forceinline__ void gload16(const void* g, void* l) {
    __builtin_amdgcn_global_load_lds(
        (const __attribute__((address_space(1))) unsigned int*)g,
        (__attribute__((address_space(3))) unsigned int*)l, 16, 0, 0);
}
static __device__ __forceinline__ ushort8 cvt8(const float* src) {
    const float4 u = ((const float4*)src)[0];
    const float4 v = ((const float4*)src)[1];
    ushort8 o;
    o[0] = f2bf(u.x); o[1] = f2bf(u.y); o[2] = f2bf(u.z); o[3] = f2bf(u.w);
    o[4] = f2bf(v.x); o[5] = f2bf(v.y); o[6] = f2bf(v.z); o[7] = f2bf(v.w);
    return o;
}

// ---- merged conversion kernel ----
__global__ __launch_bounds__(256) void conv_kernel(
    const float* __restrict__ x, const float* __restrict__ h,
    const float* __restrict__ Wx, const float* __restrict__ Wh,
    unsigned short* __restrict__ A, unsigned short* __restrict__ W)
{
    const int bidx = blockIdx.x;
    if (bidx < 8192) {
        const int id = bidx * 256 + threadIdx.x;
        const int base = id * 8;
        const int b = base >> 11;
        const int k = base & 2047;
        const float* src = (k < 1024) ? (x + (size_t)b * 1024 + k)
                                      : (h + (size_t)b * 1024 + (k - 1024));
        *(ushort8*)(A + base) = cvt8(src);
    } else {
        const int id = (bidx - 8192) * 256 + threadIdx.x;
        const int base = id * 8;
        const int n = base >> 11;
        const int k = base & 2047;
        const int jb = n >> 8, wn = (n >> 6) & 3, g = (n >> 4) & 3, jj = n & 15;
        const int srow = (g << 10) + (jb << 6) + (wn << 4) + jj;
        const float* src = (k < 1024) ? (Wx + (size_t)srow * 1024 + k)
                                      : (Wh + (size_t)srow * 1024 + (k - 1024));
        *(ushort8*)(W + base) = cvt8(src);
    }
}

// ==================== 256x256 GEMM, 128B-row LDS, 1-barrier phases ====================
__global__ __launch_bounds__(512, 2) void lstm_gemm8(
    const unsigned short* __restrict__ Abf, const unsigned short* __restrict__ Wbf,
    const float* __restrict__ bx, const float* __restrict__ bh,
    const float* __restrict__ cprev, float* __restrict__ out)
{
    extern __shared__ unsigned short lds[];

    const int tid = threadIdx.x;
    const int lane = tid & 63;
    const int wv = tid >> 6;
    const int wm = wv >> 2;          // 0..1
    const int wn = wv & 3;           // 0..3
    const int q = lane >> 4, c = lane & 15;

    // XCD-local jb-pair ordering
    const int bid = blockIdx.x;      // 0..511
    const int xcd = bid & 7;
    const int idx = bid >> 3;        // 0..63
    const int jb  = xcd * 2 + (idx & 1);   // 0..15
    const int bb  = idx >> 1;              // 0..31
    const int b0 = bb * 256;

    const unsigned short* Ab = Abf + (size_t)b0 * K2;
    const unsigned short* Wb = Wbf + (size_t)(jb * 256) * K2;

    // staging: thread covers row = QA*64 + (tid>>3), global chunk pre-swizzled
    const size_t ssg = (size_t)(tid >> 3) * K2
                     + (size_t)(((tid & 7) ^ ((tid >> 3) & 7)) * 8);
    const unsigned sbase = (unsigned)(tid & 448) * 8;  // wave-uniform dest base

    // fragment read bases
    const unsigned arow = (unsigned)(wm * 128 + c) * 64;
    const unsigned brow = 16384u + (unsigned)(wn * 64 + c) * 64;
    const unsigned cach = (unsigned)((q ^ (c & 7)) << 3);

    f32x4 acc[8][4];
#pragma unroll
    for (int m = 0; m < 8; ++m)
#pragma unroll
        for (int g = 0; g < 4; ++g) acc[m][g] = f32x4{0.f, 0.f, 0.f, 0.f};

    bf16x8 av[4], bv[4];

#define STG(BUF, ISB, QA, T) do {                                              \
    const unsigned short* _s = (ISB) ? Wb : Ab;                                \
    gload16(_s + ssg + (size_t)(QA) * 64 * K2 + (size_t)((T) & 31) * 64,       \
            &lds[(BUF) * 32768 + (ISB) * 16384 + (QA) * 4096 + sbase]);        \
} while (0)

#define LOADA(BUF, KS, MH) do {                                                \
    const unsigned short* _p = lds + (BUF) * 32768 + (MH) * 4096 + arow        \
                             + (cach ^ ((KS) * 32));                           \
    av[0] = *(const bf16x8*)(_p);                                              \
    av[1] = *(const bf16x8*)(_p + 1024);                                       \
    av[2] = *(const bf16x8*)(_p + 2048);                                       \
    av[3] = *(const bf16x8*)(_p + 3072);                                       \
} while (0)

#define LOADB(BUF, KS) do {                                                    \
    const unsigned short* _p = lds + (BUF) * 32768 + brow                      \
                             + (cach ^ ((KS) * 32));                           \
    bv[0] = *(const bf16x8*)(_p);                                              \
    bv[1] = *(const bf16x8*)(_p + 1024);                                       \
    bv[2] = *(const bf16x8*)(_p + 2048);                                       \
    bv[3] = *(const bf16x8*)(_p + 3072);                                       \
} while (0)

#define MFMA16(MH) do {                                                        \
    __builtin_amdgcn_s_setprio(1);                                             \
    _Pragma("unroll")                                                          \
    for (int _i = 0; _i < 4; ++_i)                                             \
        _Pragma("unroll")                                                      \
        for (int _g = 0; _g < 4; ++_g)                                         \
            acc[(MH) * 4 + _i][_g] = __builtin_amdgcn_mfma_f32_16x16x32_bf16(  \
                av[_i], bv[_g], acc[(MH) * 4 + _i][_g], 0, 0, 0);              \
    __builtin_amdgcn_s_setprio(0);                                             \
} while (0)

#define BAR()  __builtin_amdgcn_s_barrier()
#define WVM2() asm volatile("s_waitcnt vmcnt(2)" ::: "memory")

// 4 phases per K-tile, ONE barrier each (phase-end); compiler emits counted
// lgkm waits for ds_read->MFMA. vmcnt(2) at p1/p4.
#define TILE(BUF, T1) do {                                                     \
    LOADA(BUF, 0, 0); LOADB(BUF, 0);                                           \
    STG((BUF) ^ 1, 1, 0, T1); STG((BUF) ^ 1, 1, 1, T1);                        \
    MFMA16(0); WVM2(); BAR();                                                  \
    LOADA(BUF, 0, 1);                                                          \
    STG((BUF) ^ 1, 1, 2, T1); STG((BUF) ^ 1, 1, 3, T1);                        \
    MFMA16(1); BAR();                                                          \
    LOADA(BUF, 1, 0); LOADB(BUF, 1);                                           \
    STG((BUF) ^ 1, 0, 0, T1); STG((BUF) ^ 1, 0, 2, T1);                        \
    MFMA16(0); BAR();                                                          \
    LOADA(BUF, 1, 1);                                                          \
    STG((BUF) ^ 1, 0, 1, T1); STG((BUF) ^ 1, 0, 3, T1);                        \
    MFMA16(1); WVM2(); BAR();                                                  \
} while (0)

    // prologue: tile0 -> buf0: B q0-q3, A q0,q2,q1,q3 (8 gloads);
    // vmcnt(2) retires B + A-q0,q2 (leaves A-q1,q3 = steady-state carry-in)
    STG(0, 1, 0, 0); STG(0, 1, 1, 0); STG(0, 1, 2, 0); STG(0, 1, 3, 0);
    STG(0, 0, 0, 0); STG(0, 0, 2, 0); STG(0, 0, 1, 0); STG(0, 0, 3, 0);
    WVM2();
    BAR();

    for (int u = 0; u < 32; u += 2) {
        TILE(0, u + 1);   // tile u   (buf0), stage u+1 -> buf1
        TILE(1, u + 2);   // tile u+1 (buf1), stage u+2 -> buf0 (u=30: wraps, benign)
    }

#undef TILE
#undef STG
#undef LOADA
#undef LOADB
#undef MFMA16

    // ---- fused LSTM epilogue (C/D: col=lane&15, row=(lane>>4)*4+rr) ----
    const int j = jb * 64 + wn * 16 + c;
    const float bI = bx[j] + bh[j];
    const float bF = bx[1024 + j] + bh[1024 + j];
    const float bG = bx[2048 + j] + bh[2048 + j];
    const float bO = bx[3072 + j] + bh[3072 + j];
#pragma unroll
    for (int mt = 0; mt < 8; ++mt) {
#pragma unroll
        for (int rr = 0; rr < 4; ++rr) {
            const int row = b0 + wm * 128 + mt * 16 + q * 4 + rr;
            const size_t off = (size_t)row * 1024 + j;
            const float iv = sigf(acc[mt][0][rr] + bI);
            const float fv = sigf(acc[mt][1][rr] + bF);
            const float gv = tanhft(acc[mt][2][rr] + bG);
            const float ov = sigf(acc[mt][3][rr] + bO);
            const float cp = cprev[off];
            const float nc = fv * cp + iv * gv;
            out[off] = ov * tanhft(nc);   // new_h
            out[BH + off] = nc;           // new_c
        }
    }
}

// ================== fallback (R2 128^2 kernel) if ws too small ==================
__global__ __launch_bounds__(256) void lstm_fallback(
    const float* __restrict__ incoming, const float* __restrict__ state,
    const float* __restrict__ Wx, const float* __restrict__ bx,
    const float* __restrict__ Wh, const float* __restrict__ bh,
    float* __restrict__ out)
{
    __shared__ unsigned short lA[128 * 64];
    __shared__ unsigned short lW[128 * 64];
    const int t = threadIdx.x;
    const int lane = t & 63;
    const int wv = t >> 6;
    const int q = lane >> 4;
    const int c = lane & 15;
    const int j0 = blockIdx.x * 32;
    const int b0 = blockIdx.y * 128;
    const float* hprev = state;
    const float* cprev = state + (size_t)BH;

    f32x4 acc[2][8];
#pragma unroll
    for (int mt = 0; mt < 2; ++mt)
#pragma unroll
        for (int nt = 0; nt < 8; ++nt)
            acc[mt][nt] = f32x4{0.f, 0.f, 0.f, 0.f};

    const int sr = t >> 3;
    const int sk8 = t & 7;

    for (int it = 0; it < 32; ++it) {
        const bool first = (it < 16);
        const float* As = first ? incoming : hprev;
        const float* Ws = first ? Wx : Wh;
        const int kk = first ? it * 64 : it * 64 - 1024;
#pragma unroll
        for (int i = 0; i < 4; ++i) {
            const int r = i * 32 + sr;
            *(ushort8*)&lA[r * 64 + ((sk8 ^ (r & 7)) * 8)] =
                cvt8(As + (size_t)(b0 + r) * 1024 + kk + sk8 * 8);
        }
#pragma unroll
        for (int i = 0; i < 4; ++i) {
            const int n = i * 32 + sr;
            const int grow = ((n >> 5) << 10) + j0 + (n & 31);
            *(ushort8*)&lW[n * 64 + ((sk8 ^ (n & 7)) * 8)] =
                cvt8(Ws + (size_t)grow * 1024 + kk + sk8 * 8);
        }
        __syncthreads();
#pragma unroll
        for (int ks = 0; ks < 2; ++ks) {
            const int k8a = ks * 4 + q;
            bf16x8 av[2], bv[8];
#pragma unroll
            for (int mt = 0; mt < 2; ++mt) {
                const int r = wv * 32 + mt * 16 + c;
                av[mt] = *(const bf16x8*)&lA[r * 64 + ((k8a ^ (r & 7)) * 8)];
            }
#pragma unroll
            for (int nt = 0; nt < 8; ++nt) {
                const int n = nt * 16 + c;
                bv[nt] = *(const bf16x8*)&lW[n * 64 + ((k8a ^ (n & 7)) * 8)];
            }
#pragma unroll
            for (int mt = 0; mt < 2; ++mt)
#pragma unroll
                for (int nt = 0; nt < 8; ++nt)
                    acc[mt][nt] = __builtin_amdgcn_mfma_f32_16x16x32_bf16(
                        av[mt], bv[nt], acc[mt][nt], 0, 0, 0);
        }
        __syncthreads();
    }

    const int b0r = b0 + wv * 32;
#pragma unroll
    for (int jt = 0; jt < 2; ++jt) {
        const int j = j0 + jt * 16 + c;
        const float bI = bx[j] + bh[j];
        const float bF = bx[1024 + j] + bh[1024 + j];
        const float bG = bx[2048 + j] + bh[2048 + j];
        const float bO = bx[3072 + j] + bh[3072 + j];
#pragma unroll
        for (int mt = 0; mt < 2; ++mt) {
#pragma unroll
            for (int rr = 0; rr < 4; ++rr) {
                const int row = b0r + mt * 16 + q * 4 + rr;
                const size_t off = (size_t)row * 1024 + j;
                const float iv = sigf(acc[mt][0 + jt][rr] + bI);
                const float fv = sigf(acc[mt][2 + jt][rr] + bF);
                const float gv = tanhft(acc[mt][4 + jt][rr] + bG);
                const float ov = sigf(acc[mt][6 + jt][rr] + bO);
                const float cp = cprev[off];
                const float nc = fv * cp + iv * gv;
                out[off] = ov * tanhft(nc);
                out[BH + off] = nc;
            }
        }
    }
}

extern "C" void kernel_launch(void* const* d_in, const int* in_sizes, int n_in,
                              void* d_out, int out_size, void* d_ws, size_t ws_size,
                              hipStream_t stream) {
    const float* incoming = (const float*)d_in[0];
    const float* state    = (const float*)d_in[1];
    const float* Wx       = (const float*)d_in[2];
    const float* bx       = (const float*)d_in[3];
    const float* Wh       = (const float*)d_in[4];
    const float* bh       = (const float*)d_in[5];
    float* out = (float*)d_out;

    const float* hprev = state;
    const float* cprev = state + (size_t)BH;

    const size_t A_bytes = (size_t)B_DIM * K2 * 2;       // 32 MiB
    const size_t W_bytes = (size_t)4 * H_DIM * K2 * 2;   // 16 MiB

    if (ws_size >= A_bytes + W_bytes) {
        unsigned short* Abf = (unsigned short*)d_ws;
        unsigned short* Wbf = (unsigned short*)((char*)d_ws + A_bytes);
        conv_kernel<<<dim3(12288), dim3(256), 0, stream>>>(
            incoming, hprev, Wx, Wh, Abf, Wbf);
        (void)hipFuncSetAttribute((const void*)lstm_gemm8,
                                  hipFuncAttributeMaxDynamicSharedMemorySize, 131072);
        lstm_gemm8<<<dim3(512), dim3(512), 131072, stream>>>(
            Abf, Wbf, bx, bh, cprev, out);
    } else {
        dim3 grid(H_DIM / 32, B_DIM / 128);
        lstm_fallback<<<grid, dim3(256), 0, stream>>>(
            incoming, state, Wx, bx, Wh, bh, out);
    }
}